// Round 11
// baseline (146.905 us; speedup 1.0000x reference)
//
#include <hip/hip_runtime.h>

// DilatedCausalSelfAttention on MI355X (gfx950)
// ws layout (91.5 MB):
//   xi_bf   [8192][1024] bf16   @ 0          (16 MB)  -- dead after gemm_qkv
//   win_bf  [3072][1024] bf16   @ 16777216   (6 MB)
//   wout_bf [1024][1024] bf16   @ 23068672   (2 MB)
//   qkv     [3][8192][1024] bf16 @ 25165824  (48 MB)  -- plane0=Q, plane1=K,
//             plane2 = V TRANSPOSED as vt[256 bh][64 d][512 k]
//   o_bf    [8192][1024] bf16   @ 75497472   (16 MB)

typedef unsigned short u16;
typedef short short8 __attribute__((ext_vector_type(8)));
typedef short short4v __attribute__((ext_vector_type(4)));
typedef float f32x4 __attribute__((ext_vector_type(4)));

__device__ __forceinline__ u16 f2bf(float f) {
  unsigned u = __builtin_bit_cast(unsigned, f);
  u += 0x7FFFu + ((u >> 16) & 1u);   // RNE
  return (u16)(u >> 16);
}

__device__ __forceinline__ void gload_lds16(const void* g, void* l) {
  __builtin_amdgcn_global_load_lds((const __attribute__((address_space(1))) void*)g,
                                   (__attribute__((address_space(3))) void*)l,
                                   16, 0, 0);
}

#define SBAR() asm volatile("s_barrier" ::: "memory")

// ---------------- fused input conversion (gather-x | w_in | w_out) ----------------
__global__ void conv_all(const float* __restrict__ x,
                         const float* __restrict__ w_in,
                         const float* __restrict__ w_out,
                         u16* __restrict__ xi, u16* __restrict__ win,
                         u16* __restrict__ wout) {
  const int b = blockIdx.x;
  if (b < 4096) {
    int t = b * 256 + threadIdx.x;
    int row = t >> 7;
    int col = (t & 127) << 3;
    size_t src = ((size_t)((row >> 9) << 11) + ((row & 511) << 2)) * 1024 + col;
    float4 v0 = *(const float4*)(x + src);
    float4 v1 = *(const float4*)(x + src + 4);
    short8 o;
    o[0] = f2bf(v0.x); o[1] = f2bf(v0.y); o[2] = f2bf(v0.z); o[3] = f2bf(v0.w);
    o[4] = f2bf(v1.x); o[5] = f2bf(v1.y); o[6] = f2bf(v1.z); o[7] = f2bf(v1.w);
    *(short8*)(xi + (size_t)row * 1024 + col) = o;
  } else {
    const float* src;
    u16* dst;
    int t;
    if (b < 5632) { t = (b - 4096) * 256 + threadIdx.x; src = w_in;  dst = win; }
    else          { t = (b - 5632) * 256 + threadIdx.x; src = w_out; dst = wout; }
    size_t base = (size_t)t * 8;
    float4 v0 = *(const float4*)(src + base);
    float4 v1 = *(const float4*)(src + base + 4);
    short8 o;
    o[0] = f2bf(v0.x); o[1] = f2bf(v0.y); o[2] = f2bf(v0.z); o[3] = f2bf(v0.w);
    o[4] = f2bf(v1.x); o[5] = f2bf(v1.y); o[6] = f2bf(v1.z); o[7] = f2bf(v1.w);
    *(short8*)(dst + base) = o;
  }
}

// ============== QKV GEMM: 256x256 block, BK=32, triple-buffered read-ahead ==============
// grid 384 (32x12), 512 thr = 8 waves (2M x 4N), wave tile 128x64, acc 8x4 f32x4.
// LDS 96 KiB = 3 bufs x {A[256][32], B[256][32]}; swizzle chunk^= (row&3)^((row>>2)&3)
// -> 2-way bank aliasing (free). One 16x16x32 MFMA consumes full BK per (mi,ni).
// Read-ahead: READ frags(t+1) issued before MFMA(t); counted vmcnt(4); 1 SBAR/tile.
__global__ __launch_bounds__(512) void gemm_qkv32(
    const u16* __restrict__ A, const u16* __restrict__ B,
    const float* __restrict__ bias, u16* __restrict__ C) {
  constexpr int K = 1024, NT = 32;
  __shared__ u16 lds[3][16384];   // [buf][A:0..8191 | B:8192..16383]

  const int tid = threadIdx.x;
  const int w = tid >> 6, lane = tid & 63;
  const int wm = w >> 2, wn = w & 3;
  const int g = lane >> 4, lq = lane & 15;

  // bijective XCD swizzle (384 % 8 == 0)
  const int s = (blockIdx.x & 7) * 48 + (blockIdx.x >> 3);
  const int m0 = (s / 12) * 256, n0 = (s % 12) * 256;

  // staging: one call = 512 thr x 16B = 8KB = 128 rows x 64B; thread covers
  // row r = tid>>2, phys chunk tid&3, logical chunk jch = phys ^ (r&3) ^ ((r>>2)&3)
  const int r_ = tid >> 2;
  const int jch = (tid & 3) ^ (r_ & 3) ^ ((r_ >> 2) & 3);
  const u16* Ab = A + (size_t)(m0 + r_) * K + jch * 8;
  const u16* Bb = B + (size_t)(n0 + r_) * K + jch * 8;

#define SA32(buf_, q, kt) gload_lds16(Ab + (size_t)(q) * 128 * K + (kt) * 32, &lds[buf_][(q) * 4096 + tid * 8])
#define SB32(buf_, q, kt) gload_lds16(Bb + (size_t)(q) * 128 * K + (kt) * 32, &lds[buf_][8192 + (q) * 4096 + tid * 8])
#define STAGE4(kt)                                                                 \
  { const int nb_ = (kt) % 3;                                                      \
    SA32(nb_, 0, kt); SA32(nb_, 1, kt); SB32(nb_, 0, kt); SB32(nb_, 1, kt); }

  // read swizzle constant per lane: row = base + mi*16 + lq -> (row&3)=(lq&3),
  // ((row>>2)&3)=((lq>>2)&3) since all bases are multiples of 16.
  const int xsw = ((lq & 3) ^ ((lq >> 2) & 3));
  const int arow = wm * 128 + lq;
  const int brow = wn * 64 + lq;
  const int rch = (g ^ xsw) * 8;

#define READ_T(aset, bset, tile_)                                                  \
  { const int bufr = (tile_) % 3;                                                  \
    _Pragma("unroll") for (int mi = 0; mi < 8; ++mi)                               \
      aset[mi] = *(const short8*)(&lds[bufr][(arow + mi * 16) * 32 + rch]);        \
    _Pragma("unroll") for (int ni = 0; ni < 4; ++ni)                               \
      bset[ni] = *(const short8*)(&lds[bufr][8192 + (brow + ni * 16) * 32 + rch]); }

#define MFMA_T(aset, bset)                                                         \
  __builtin_amdgcn_s_setprio(1);                                                   \
  _Pragma("unroll") for (int mi = 0; mi < 8; ++mi)                                 \
    _Pragma("unroll") for (int ni = 0; ni < 4; ++ni)                               \
      acc[mi][ni] = __builtin_amdgcn_mfma_f32_16x16x32_bf16(                       \
          aset[mi], bset[ni], acc[mi][ni], 0, 0, 0);                               \
  __builtin_amdgcn_s_setprio(0);

  f32x4 acc[8][4] = {};
  short8 aA[8], bA[4], aB[8], bB[4];

  // prologue
  STAGE4(0); STAGE4(1);
  asm volatile("s_waitcnt vmcnt(4)" ::: "memory");
  SBAR();
  READ_T(aA, bA, 0);

#pragma unroll 1
  for (int tt = 0; tt < NT; tt += 2) {
    // half A: compute tile tt, read tile tt+1
    if (tt + 2 < NT) STAGE4(tt + 2);
    if (tt + 2 < NT) { asm volatile("s_waitcnt vmcnt(4)" ::: "memory"); }
    else             { asm volatile("s_waitcnt vmcnt(0)" ::: "memory"); }
    asm volatile("s_waitcnt lgkmcnt(0)" ::: "memory");
    SBAR();
    READ_T(aB, bB, tt + 1);
    MFMA_T(aA, bA);

    // half B: compute tile tt+1, read tile tt+2
    if (tt + 3 < NT) STAGE4(tt + 3);
    if (tt + 3 < NT) { asm volatile("s_waitcnt vmcnt(4)" ::: "memory"); }
    else             { asm volatile("s_waitcnt vmcnt(0)" ::: "memory"); }
    asm volatile("s_waitcnt lgkmcnt(0)" ::: "memory");
    SBAR();
    if (tt + 2 < NT) READ_T(aA, bA, tt + 2);
    MFMA_T(aB, bB);
  }

  // epilogue: Q/K planes or transposed V
  if (n0 < 2048) {
#pragma unroll
    for (int mi = 0; mi < 8; ++mi) {
#pragma unroll
      for (int ni = 0; ni < 4; ++ni) {
        const int col = n0 + wn * 64 + ni * 16 + lq;
        const float bv = bias[col];
        u16* dst = C + (size_t)(col >> 10) * 8388608 + (col & 1023);
#pragma unroll
        for (int r = 0; r < 4; ++r) {
          const int m = m0 + wm * 128 + mi * 16 + g * 4 + r;
          dst[(size_t)m * 1024] = f2bf(acc[mi][ni][r] + bv);
        }
      }
    }
  } else {
    u16* vt = C + 16777216;
#pragma unroll
    for (int mi = 0; mi < 8; ++mi) {
      const int m4 = m0 + wm * 128 + mi * 16 + g * 4;
      const int bs = m4 >> 9, k = m4 & 511;
#pragma unroll
      for (int ni = 0; ni < 4; ++ni) {
        const int cv = n0 - 2048 + wn * 64 + ni * 16 + lq;
        const int h = cv >> 6, d = cv & 63;
        const float bv = bias[cv + 2048];
        short4v pk;
#pragma unroll
        for (int r = 0; r < 4; ++r) pk[r] = (short)f2bf(acc[mi][ni][r] + bv);
        *(short4v*)(&vt[(size_t)((bs * 16 + h) * 64 + d) * 512 + k]) = pk;
      }
    }
  }
#undef SA32
#undef SB32
#undef STAGE4
#undef READ_T
#undef MFMA_T
}

// ============== out-proj GEMM: 128x256 tile, BK=64, triple-buffered read-ahead ==============
// (proven r10 structure) 256 blocks = 1 exact round; f32 scatter + coalesced zero-fill.
__global__ __launch_bounds__(512) void gemm_out(
    const u16* __restrict__ A, const u16* __restrict__ B,
    const float* __restrict__ bias, float* __restrict__ O) {
  constexpr int K = 1024, NT = 16;
  __shared__ u16 lds[3][24576];   // [buf][A:0..8191 | B:8192..24575]

  const int tid = threadIdx.x;
  const int w = tid >> 6, lane = tid & 63;
  const int wm = w >> 2, wn = w & 3;
  const int g = lane >> 4, lq = lane & 15;

  const int per = gridDim.x >> 3;
  const int s = (blockIdx.x & 7) * per + (blockIdx.x >> 3);
  const int m0 = (s >> 2) * 128, n0 = (s & 3) * 256;

  const int srow = w * 8 + (lane >> 3);
  const int jch = (lane & 7) ^ ((lane >> 3) & 7);
  const u16* Ab = A + (size_t)(m0 + srow) * K + jch * 8;
  const u16* Bb = B + (size_t)(n0 + srow) * K + jch * 8;
  const int ldst = w * 512 + lane * 8;

#define SA(buf_, qd, kt) gload_lds16(Ab + (size_t)(qd) * 64 * K + (kt) * 64, &lds[buf_][(qd) * 4096 + ldst])
#define SB(buf_, qd, kt) gload_lds16(Bb + (size_t)(qd) * 64 * K + (kt) * 64, &lds[buf_][8192 + (qd) * 4096 + ldst])
#define STAGE6(kt)                                                                 \
  { const int nb_ = (kt) % 3;                                                      \
    SA(nb_, 0, kt); SA(nb_, 1, kt);                                                \
    SB(nb_, 0, kt); SB(nb_, 1, kt); SB(nb_, 2, kt); SB(nb_, 3, kt); }

  const int xw = lq & 7;
  const int arow = wm * 64 + lq;
  const int brow = wn * 64 + lq;

#define READ_TILE(aset, bset, tile_)                                               \
  { const int bufr = (tile_) % 3;                                                  \
    _Pragma("unroll") for (int kc = 0; kc < 2; ++kc) {                             \
      _Pragma("unroll") for (int mi = 0; mi < 4; ++mi)                             \
        aset[mi + 4 * kc] = *(const short8*)(                                      \
            &lds[bufr][(arow + mi * 16) * 64 + ((kc * 4 + g) ^ xw) * 8]);          \
      _Pragma("unroll") for (int ni = 0; ni < 4; ++ni)                             \
        bset[ni + 4 * kc] = *(const short8*)(                                      \
            &lds[bufr][8192 + (brow + ni * 16) * 64 + ((kc * 4 + g) ^ xw) * 8]);   \
    } }

#define MFMA_TILE(aset, bset)                                                      \
  __builtin_amdgcn_s_setprio(1);                                                   \
  _Pragma("unroll") for (int kc = 0; kc < 2; ++kc)                                 \
    _Pragma("unroll") for (int mi = 0; mi < 4; ++mi)                               \
      _Pragma("unroll") for (int ni = 0; ni < 4; ++ni)                             \
        acc[mi][ni] = __builtin_amdgcn_mfma_f32_16x16x32_bf16(                     \
            aset[mi + 4 * kc], bset[ni + 4 * kc], acc[mi][ni], 0, 0, 0);           \
  __builtin_amdgcn_s_setprio(0);

  f32x4 acc[4][4] = {};
  short8 aA[8], bA[8], aB[8], bB[8];

  STAGE6(0); STAGE6(1);
  asm volatile("s_waitcnt vmcnt(6)" ::: "memory");
  SBAR();
  READ_TILE(aA, bA, 0);

#pragma unroll 1
  for (int tt = 0; tt < NT; tt += 2) {
    if (tt + 2 < NT) STAGE6(tt + 2);
    if (tt + 2 < NT) { asm volatile("s_waitcnt vmcnt(6)" ::: "memory"); }
    else             { asm volatile("s_waitcnt vmcnt(0)" ::: "memory"); }
    asm volatile("s_waitcnt lgkmcnt(0)" ::: "memory");
    SBAR();
    READ_TILE(aB, bB, tt + 1);
    MFMA_TILE(aA, bA);

    if (tt + 3 < NT) STAGE6(tt + 3);
    if (tt + 3 < NT) { asm volatile("s_waitcnt vmcnt(6)" ::: "memory"); }
    else             { asm volatile("s_waitcnt vmcnt(0)" ::: "memory"); }
    asm volatile("s_waitcnt lgkmcnt(0)" ::: "memory");
    SBAR();
    if (tt + 2 < NT) READ_TILE(aA, bA, tt + 2);
    MFMA_TILE(aB, bB);
  }

#pragma unroll
  for (int mi = 0; mi < 4; ++mi) {
#pragma unroll
    for (int ni = 0; ni < 4; ++ni) {
      const int col = n0 + wn * 64 + ni * 16 + lq;
      const float bv = bias[col];
#pragma unroll
      for (int r = 0; r < 4; ++r) {
        const int m = m0 + wm * 64 + mi * 16 + g * 4 + r;
        const int orow = ((m >> 9) << 11) + ((m & 511) << 2);
        O[(size_t)orow * 1024 + col] = acc[mi][ni][r] + bv;
      }
    }
  }
  // coalesced zero-fill: rows orow+1..3, this block's 128 m x 256 cols.
  for (int i = 0; i < 48; ++i) {
    const int idx = i * 512 + tid;
    const int z = idx >> 13;
    const int mm = (idx & 8191) >> 6;
    const int ch = idx & 63;
    const int m = m0 + mm;
    const int orow = ((m >> 9) << 11) + ((m & 511) << 2) + 1 + z;
    *(float4*)(O + (size_t)orow * 1024 + n0 + ch * 4) =
        make_float4(0.f, 0.f, 0.f, 0.f);
  }
#undef SA
#undef SB
#undef STAGE6
#undef READ_TILE
#undef MFMA_TILE
}

// ---------------- attention: whole-head blocks, K/V LDS-resident ----------------
__global__ __launch_bounds__(512) void attn_kernel(const u16* __restrict__ qkv,
                                                   u16* __restrict__ o_ws) {
  __shared__ u16 Ks[512 * 64];    // row r, chunk c at phys (c ^ (r&7)): 64 KB
  __shared__ u16 Vs[64 * 512];    // row d, chunk c at phys (c ^ (d&7)): 64 KB
  __shared__ u16 Pl[8][16][40];   // per-wave P tile [q][k0..31]

  const int tid = threadIdx.x;
  const int w = tid >> 6, lane = tid & 63;
  const int g = lane >> 4, lq = lane & 15;
  const int bh = blockIdx.x;
  const int bs = bh >> 4, h = bh & 15;

  const u16* baseq = qkv + (size_t)bs * 512 * 1024 + h * 64;
  const u16* basek = qkv + 8388608 + (size_t)bs * 512 * 1024 + h * 64;
  const u16* vhead = qkv + 16777216 + (size_t)bh * 32768;

  {
    const int rsub = lane >> 3;
    const int csw = (lane & 7) ^ rsub;
#pragma unroll
    for (int i = 0; i < 8; ++i) {
      const int step = i * 8 + w;
      gload_lds16(basek + (size_t)(step * 8 + rsub) * 1024 + csw * 8,
                  &Ks[step * 512 + lane * 8]);
    }
#pragma unroll
    for (int i = 0; i < 8; ++i) {
      const int d = i * 8 + w;
      gload_lds16(vhead + (size_t)d * 512 + (lane ^ (d & 7)) * 8,
                  &Vs[d * 512 + lane * 8]);
    }
  }
  __syncthreads();   // drains vmcnt; only barrier in the kernel

  const int xw = lq & 7;
#pragma unroll 1
  for (int qi = 0; qi < 4; ++qi) {
    const int qt = ((qi & 1) ? (15 - w) : w) + (qi >> 1) * 16;
    const int q0 = qt * 16;
    const short8 qf0 = *(const short8*)(baseq + (size_t)(q0 + lq) * 1024 + g * 8);
    const short8 qf1 = *(const short8*)(baseq + (size_t)(q0 + lq) * 1024 + 32 + g * 8);
    f32x4 oacc[4] = {};
    float l_r[4] = {0.f, 0.f, 0.f, 0.f};
    const int nst = (qt + 2) >> 1;       // 32-col k-steps
#pragma unroll 1
    for (int kk = 0; kk < nst; ++kk) {
      const int kb = kk * 32;
      const bool last = (kk == nst - 1);
      f32x4 s[2];
#pragma unroll
      for (int tt = 0; tt < 2; ++tt) {
        const int r = kb + tt * 16 + lq;
        short8 klo = *(const short8*)(&Ks[r * 64 + ((g ^ xw) * 8)]);
        short8 khi = *(const short8*)(&Ks[r * 64 + (((4 + g) ^ xw) * 8)]);
        f32x4 z = {};
        z = __builtin_amdgcn_mfma_f32_16x16x32_bf16(qf0, klo, z, 0, 0, 0);
        z = __builtin_amdgcn_mfma_f32_16x16x32_bf16(qf1, khi, z, 0, 0, 0);
        s[tt] = z;
      }
#pragma unroll
      for (int tt = 0; tt < 2; ++tt) {
#pragma unroll
        for (int r = 0; r < 4; ++r) {
          float p = __expf(s[tt][r] * 0.125f);
          if (last && (kb + tt * 16 + lq > q0 + g * 4 + r)) p = 0.f;
          l_r[r] += p;
          Pl[w][g * 4 + r][tt * 16 + lq] = f2bf(p);
        }
      }
      short8 pf = *(const short8*)(&Pl[w][lq][g * 8]);
#pragma unroll
      for (int dt = 0; dt < 4; ++dt) {
        const int vr = dt * 16 + lq;
        short8 vf = *(const short8*)(&Vs[vr * 512 + ((((kb >> 3) + g) ^ xw) * 8)]);
        oacc[dt] = __builtin_amdgcn_mfma_f32_16x16x32_bf16(pf, vf, oacc[dt], 0, 0, 0);
      }
    }
#pragma unroll
    for (int r = 0; r < 4; ++r) {
      float l = l_r[r];
      l += __shfl_xor(l, 1);
      l += __shfl_xor(l, 2);
      l += __shfl_xor(l, 4);
      l += __shfl_xor(l, 8);
      const float inv = 1.0f / l;
      const int q = q0 + g * 4 + r;
      u16* dst = o_ws + (size_t)(bs * 512 + q) * 1024 + h * 64;
#pragma unroll
      for (int dt = 0; dt < 4; ++dt) dst[dt * 16 + lq] = f2bf(oacc[dt][r] * inv);
    }
  }
}

// ---------------- launch ----------------
extern "C" void kernel_launch(void* const* d_in, const int* in_sizes, int n_in,
                              void* d_out, int out_size, void* d_ws, size_t ws_size,
                              hipStream_t stream) {
  const float* x     = (const float*)d_in[0];
  const float* w_in  = (const float*)d_in[1];
  const float* b_in  = (const float*)d_in[2];
  const float* w_out = (const float*)d_in[3];
  const float* b_out = (const float*)d_in[4];

  char* ws = (char*)d_ws;
  u16* xi_bf   = (u16*)(ws);
  u16* win_bf  = (u16*)(ws + 16777216);
  u16* wout_bf = (u16*)(ws + 16777216 + 6291456);
  u16* qkv     = (u16*)(ws + 16777216 + 6291456 + 2097152);
  u16* o_bf    = (u16*)(ws + 16777216 + 6291456 + 2097152 + 50331648);

  // 1. fused input conversion (x-gather + w_in + w_out)
  conv_all<<<6144, 256, 0, stream>>>(x, w_in, w_out, xi_bf, win_bf, wout_bf);
  // 2. QKV projection (256x256, BK=32, fused V transpose into plane2)
  gemm_qkv32<<<384, 512, 0, stream>>>(xi_bf, win_bf, b_in, qkv);
  // 3. attention (whole-head blocks, K/V LDS-resident)
  attn_kernel<<<256, 512, 0, stream>>>(qkv, o_bf);
  // 4. output projection + scatter + zero-fill, 256 blocks = 1 exact round
  gemm_out<<<256, 512, 0, stream>>>(o_bf, wout_bf, b_out, (float*)d_out);
}

// Round 12
// 135.494 us; speedup vs baseline: 1.0842x; 1.0842x over previous
//
#include <hip/hip_runtime.h>

// DilatedCausalSelfAttention on MI355X (gfx950)
// ws layout (91.5 MB):
//   xi_bf   [8192][1024] bf16   @ 0          (16 MB)  -- dead after gemm_qkv
//   win_bf  [3072][1024] bf16   @ 16777216   (6 MB)
//   wout_bf [1024][1024] bf16   @ 23068672   (2 MB)
//   qkv     [3][8192][1024] bf16 @ 25165824  (48 MB)  -- plane0=Q, plane1=K,
//             plane2 = V TRANSPOSED as vt[256 bh][64 d][512 k]
//   o_bf    [8192][1024] bf16   @ 75497472   (16 MB)

typedef unsigned short u16;
typedef short short8 __attribute__((ext_vector_type(8)));
typedef short short4v __attribute__((ext_vector_type(4)));
typedef float f32x4 __attribute__((ext_vector_type(4)));

__device__ __forceinline__ u16 f2bf(float f) {
  unsigned u = __builtin_bit_cast(unsigned, f);
  u += 0x7FFFu + ((u >> 16) & 1u);   // RNE
  return (u16)(u >> 16);
}

__device__ __forceinline__ void gload_lds16(const void* g, void* l) {
  __builtin_amdgcn_global_load_lds((const __attribute__((address_space(1))) void*)g,
                                   (__attribute__((address_space(3))) void*)l,
                                   16, 0, 0);
}

#define SBAR() asm volatile("s_barrier" ::: "memory")

// ---------------- fused input conversion (gather-x | w_in | w_out) ----------------
__global__ void conv_all(const float* __restrict__ x,
                         const float* __restrict__ w_in,
                         const float* __restrict__ w_out,
                         u16* __restrict__ xi, u16* __restrict__ win,
                         u16* __restrict__ wout) {
  const int b = blockIdx.x;
  if (b < 4096) {
    int t = b * 256 + threadIdx.x;
    int row = t >> 7;
    int col = (t & 127) << 3;
    size_t src = ((size_t)((row >> 9) << 11) + ((row & 511) << 2)) * 1024 + col;
    float4 v0 = *(const float4*)(x + src);
    float4 v1 = *(const float4*)(x + src + 4);
    short8 o;
    o[0] = f2bf(v0.x); o[1] = f2bf(v0.y); o[2] = f2bf(v0.z); o[3] = f2bf(v0.w);
    o[4] = f2bf(v1.x); o[5] = f2bf(v1.y); o[6] = f2bf(v1.z); o[7] = f2bf(v1.w);
    *(short8*)(xi + (size_t)row * 1024 + col) = o;
  } else {
    const float* src;
    u16* dst;
    int t;
    if (b < 5632) { t = (b - 4096) * 256 + threadIdx.x; src = w_in;  dst = win; }
    else          { t = (b - 5632) * 256 + threadIdx.x; src = w_out; dst = wout; }
    size_t base = (size_t)t * 8;
    float4 v0 = *(const float4*)(src + base);
    float4 v1 = *(const float4*)(src + base + 4);
    short8 o;
    o[0] = f2bf(v0.x); o[1] = f2bf(v0.y); o[2] = f2bf(v0.z); o[3] = f2bf(v0.w);
    o[4] = f2bf(v1.x); o[5] = f2bf(v1.y); o[6] = f2bf(v1.z); o[7] = f2bf(v1.w);
    *(short8*)(dst + base) = o;
  }
}

// ============== pipelined GEMM: 128x256 tile, BK=64, triple-buffered ==============
// (r10-proven structure) 512 thr = 8 waves (2M x 4N), wave 64x64. LDS 144 KiB = 3 bufs,
// XOR-swizzled 8-chunk rows (128B row = full 32 banks -> conflict-free).
// READ-AHEAD: per half-iter {stage(t+2); vmcnt(6); lgkmcnt(0); SBAR;
//   READ frags(t+1) [no consumer now]; MFMA(t) from regs}.
// MODE 0: qkv epilogue (Q/K planes + transposed V). MODE 1: f32 scatter + zero-fill.
template <int NCOLS, int MODE>
__global__ __launch_bounds__(512) void gemm_pipe(
    const u16* __restrict__ A, const u16* __restrict__ B,
    const float* __restrict__ bias, void* __restrict__ Cout) {
  constexpr int K = 1024, NT = 16, NTILE = NCOLS / 256;
  __shared__ u16 lds[3][24576];   // [buf][A:0..8191 | B:8192..24575]

  const int tid = threadIdx.x;
  const int w = tid >> 6, lane = tid & 63;
  const int wm = w >> 2, wn = w & 3;
  const int g = lane >> 4, lq = lane & 15;

  // bijective XCD swizzle (gridDim.x % 8 == 0)
  const int per = gridDim.x >> 3;
  const int s = (blockIdx.x & 7) * per + (blockIdx.x >> 3);
  const int m0 = (s / NTILE) * 128, n0 = (s % NTILE) * 256;

  const int srow = w * 8 + (lane >> 3);
  const int jch = (lane & 7) ^ ((lane >> 3) & 7);
  const u16* Ab = A + (size_t)(m0 + srow) * K + jch * 8;
  const u16* Bb = B + (size_t)(n0 + srow) * K + jch * 8;
  const int ldst = w * 512 + lane * 8;

#define SA(buf_, qd, kt) gload_lds16(Ab + (size_t)(qd) * 64 * K + (kt) * 64, &lds[buf_][(qd) * 4096 + ldst])
#define SB(buf_, qd, kt) gload_lds16(Bb + (size_t)(qd) * 64 * K + (kt) * 64, &lds[buf_][8192 + (qd) * 4096 + ldst])
#define STAGE6(kt)                                                                 \
  { const int nb_ = (kt) % 3;                                                      \
    SA(nb_, 0, kt); SA(nb_, 1, kt);                                                \
    SB(nb_, 0, kt); SB(nb_, 1, kt); SB(nb_, 2, kt); SB(nb_, 3, kt); }

  const int xw = lq & 7;
  const int arow = wm * 64 + lq;
  const int brow = wn * 64 + lq;

  // read full K-64 tile: a[mi + 4*kc], b[ni + 4*kc], 16 x ds_read_b128
#define READ_TILE(aset, bset, tile_)                                               \
  { const int bufr = (tile_) % 3;                                                  \
    _Pragma("unroll") for (int kc = 0; kc < 2; ++kc) {                             \
      _Pragma("unroll") for (int mi = 0; mi < 4; ++mi)                             \
        aset[mi + 4 * kc] = *(const short8*)(                                      \
            &lds[bufr][(arow + mi * 16) * 64 + ((kc * 4 + g) ^ xw) * 8]);          \
      _Pragma("unroll") for (int ni = 0; ni < 4; ++ni)                             \
        bset[ni + 4 * kc] = *(const short8*)(                                      \
            &lds[bufr][8192 + (brow + ni * 16) * 64 + ((kc * 4 + g) ^ xw) * 8]);   \
    } }

#define MFMA_TILE(aset, bset)                                                      \
  __builtin_amdgcn_s_setprio(1);                                                   \
  _Pragma("unroll") for (int kc = 0; kc < 2; ++kc)                                 \
    _Pragma("unroll") for (int mi = 0; mi < 4; ++mi)                               \
      _Pragma("unroll") for (int ni = 0; ni < 4; ++ni)                             \
        acc[mi][ni] = __builtin_amdgcn_mfma_f32_16x16x32_bf16(                     \
            aset[mi + 4 * kc], bset[ni + 4 * kc], acc[mi][ni], 0, 0, 0);           \
  __builtin_amdgcn_s_setprio(0);

  f32x4 acc[4][4] = {};
  short8 aA[8], bA[8], aB[8], bB[8];

  // prologue: stage tile0,1; certify tile0; read tile0 into set A
  STAGE6(0); STAGE6(1);
  asm volatile("s_waitcnt vmcnt(6)" ::: "memory");
  SBAR();
  READ_TILE(aA, bA, 0);

#pragma unroll 1
  for (int tt = 0; tt < NT; tt += 2) {
    // half A: compute tile tt (set A), read tile tt+1 (set B)
    if (tt + 2 < NT) STAGE6(tt + 2);
    if (tt + 2 < NT) { asm volatile("s_waitcnt vmcnt(6)" ::: "memory"); }
    else             { asm volatile("s_waitcnt vmcnt(0)" ::: "memory"); }
    asm volatile("s_waitcnt lgkmcnt(0)" ::: "memory");
    SBAR();
    READ_TILE(aB, bB, tt + 1);
    MFMA_TILE(aA, bA);

    // half B: compute tile tt+1 (set B), read tile tt+2 (set A)
    if (tt + 3 < NT) STAGE6(tt + 3);
    if (tt + 3 < NT) { asm volatile("s_waitcnt vmcnt(6)" ::: "memory"); }
    else             { asm volatile("s_waitcnt vmcnt(0)" ::: "memory"); }
    asm volatile("s_waitcnt lgkmcnt(0)" ::: "memory");
    SBAR();
    if (tt + 2 < NT) READ_TILE(aA, bA, tt + 2);
    MFMA_TILE(aB, bB);
  }

  // ---- epilogue ----
  if (MODE == 0) {
    u16* C = (u16*)Cout;
    if (n0 < 2048) {
#pragma unroll
      for (int mi = 0; mi < 4; ++mi) {
#pragma unroll
        for (int ni = 0; ni < 4; ++ni) {
          const int col = n0 + wn * 64 + ni * 16 + lq;
          const float bv = bias[col];
          u16* dst = C + (size_t)(col >> 10) * 8388608 + (col & 1023);
#pragma unroll
          for (int r = 0; r < 4; ++r) {
            const int m = m0 + wm * 64 + mi * 16 + g * 4 + r;
            dst[(size_t)m * 1024] = f2bf(acc[mi][ni][r] + bv);
          }
        }
      }
    } else {
      u16* vt = C + 16777216;
#pragma unroll
      for (int mi = 0; mi < 4; ++mi) {
        const int m4 = m0 + wm * 64 + mi * 16 + g * 4;
        const int bs = m4 >> 9, k = m4 & 511;
#pragma unroll
        for (int ni = 0; ni < 4; ++ni) {
          const int cv = n0 - 2048 + wn * 64 + ni * 16 + lq;
          const int h = cv >> 6, d = cv & 63;
          const float bv = bias[cv + 2048];
          short4v pk;
#pragma unroll
          for (int r = 0; r < 4; ++r) pk[r] = (short)f2bf(acc[mi][ni][r] + bv);
          *(short4v*)(&vt[(size_t)((bs * 16 + h) * 64 + d) * 512 + k]) = pk;
        }
      }
    }
  } else {
    float* O = (float*)Cout;
#pragma unroll
    for (int mi = 0; mi < 4; ++mi) {
#pragma unroll
      for (int ni = 0; ni < 4; ++ni) {
        const int col = n0 + wn * 64 + ni * 16 + lq;
        const float bv = bias[col];
#pragma unroll
        for (int r = 0; r < 4; ++r) {
          const int m = m0 + wm * 64 + mi * 16 + g * 4 + r;
          const int orow = ((m >> 9) << 11) + ((m & 511) << 2);
          O[(size_t)orow * 1024 + col] = acc[mi][ni][r] + bv;
        }
      }
    }
    // coalesced zero-fill: rows orow+1..3, this block's 128 m x 256 cols.
    for (int i = 0; i < 48; ++i) {
      const int idx = i * 512 + tid;
      const int z = idx >> 13;
      const int mm = (idx & 8191) >> 6;
      const int ch = idx & 63;
      const int m = m0 + mm;
      const int orow = ((m >> 9) << 11) + ((m & 511) << 2) + 1 + z;
      *(float4*)(O + (size_t)orow * 1024 + n0 + ch * 4) =
          make_float4(0.f, 0.f, 0.f, 0.f);
    }
  }
#undef SA
#undef SB
#undef STAGE6
#undef READ_TILE
#undef MFMA_TILE
}

// ---------------- attention: whole-head blocks, K/V LDS-resident ----------------
// grid 256 = one block per (bs,h), 512 thr = 8 waves. Stage K[512][64] + Vt[64][512]
// (both XOR-swizzled) once; wave w processes Q-tiles {w, 15-w, 16+w, 31-w}.
__global__ __launch_bounds__(512) void attn_kernel(const u16* __restrict__ qkv,
                                                   u16* __restrict__ o_ws) {
  __shared__ u16 Ks[512 * 64];    // row r, chunk c at phys (c ^ (r&7)): 64 KB
  __shared__ u16 Vs[64 * 512];    // row d, chunk c at phys (c ^ (d&7)): 64 KB
  __shared__ u16 Pl[8][16][40];   // per-wave P tile [q][k0..31]

  const int tid = threadIdx.x;
  const int w = tid >> 6, lane = tid & 63;
  const int g = lane >> 4, lq = lane & 15;
  const int bh = blockIdx.x;
  const int bs = bh >> 4, h = bh & 15;

  const u16* baseq = qkv + (size_t)bs * 512 * 1024 + h * 64;
  const u16* basek = qkv + 8388608 + (size_t)bs * 512 * 1024 + h * 64;
  const u16* vhead = qkv + 16777216 + (size_t)bh * 32768;

  {
    const int rsub = lane >> 3;
    const int csw = (lane & 7) ^ rsub;
#pragma unroll
    for (int i = 0; i < 8; ++i) {
      const int step = i * 8 + w;
      gload_lds16(basek + (size_t)(step * 8 + rsub) * 1024 + csw * 8,
                  &Ks[step * 512 + lane * 8]);
    }
#pragma unroll
    for (int i = 0; i < 8; ++i) {
      const int d = i * 8 + w;
      gload_lds16(vhead + (size_t)d * 512 + (lane ^ (d & 7)) * 8,
                  &Vs[d * 512 + lane * 8]);
    }
  }
  __syncthreads();   // drains vmcnt; only barrier in the kernel

  const int xw = lq & 7;
#pragma unroll 1
  for (int qi = 0; qi < 4; ++qi) {
    const int qt = ((qi & 1) ? (15 - w) : w) + (qi >> 1) * 16;
    const int q0 = qt * 16;
    const short8 qf0 = *(const short8*)(baseq + (size_t)(q0 + lq) * 1024 + g * 8);
    const short8 qf1 = *(const short8*)(baseq + (size_t)(q0 + lq) * 1024 + 32 + g * 8);
    f32x4 oacc[4] = {};
    float l_r[4] = {0.f, 0.f, 0.f, 0.f};
    const int nst = (qt + 2) >> 1;       // 32-col k-steps
#pragma unroll 1
    for (int kk = 0; kk < nst; ++kk) {
      const int kb = kk * 32;
      const bool last = (kk == nst - 1);
      f32x4 s[2];
#pragma unroll
      for (int tt = 0; tt < 2; ++tt) {
        const int r = kb + tt * 16 + lq;
        short8 klo = *(const short8*)(&Ks[r * 64 + ((g ^ xw) * 8)]);
        short8 khi = *(const short8*)(&Ks[r * 64 + (((4 + g) ^ xw) * 8)]);
        f32x4 z = {};
        z = __builtin_amdgcn_mfma_f32_16x16x32_bf16(qf0, klo, z, 0, 0, 0);
        z = __builtin_amdgcn_mfma_f32_16x16x32_bf16(qf1, khi, z, 0, 0, 0);
        s[tt] = z;
      }
#pragma unroll
      for (int tt = 0; tt < 2; ++tt) {
#pragma unroll
        for (int r = 0; r < 4; ++r) {
          float p = __expf(s[tt][r] * 0.125f);
          if (last && (kb + tt * 16 + lq > q0 + g * 4 + r)) p = 0.f;
          l_r[r] += p;
          Pl[w][g * 4 + r][tt * 16 + lq] = f2bf(p);
        }
      }
      short8 pf = *(const short8*)(&Pl[w][lq][g * 8]);
#pragma unroll
      for (int dt = 0; dt < 4; ++dt) {
        const int vr = dt * 16 + lq;
        short8 vf = *(const short8*)(&Vs[vr * 512 + ((((kb >> 3) + g) ^ xw) * 8)]);
        oacc[dt] = __builtin_amdgcn_mfma_f32_16x16x32_bf16(pf, vf, oacc[dt], 0, 0, 0);
      }
    }
#pragma unroll
    for (int r = 0; r < 4; ++r) {
      float l = l_r[r];
      l += __shfl_xor(l, 1);
      l += __shfl_xor(l, 2);
      l += __shfl_xor(l, 4);
      l += __shfl_xor(l, 8);
      const float inv = 1.0f / l;
      const int q = q0 + g * 4 + r;
      u16* dst = o_ws + (size_t)(bs * 512 + q) * 1024 + h * 64;
#pragma unroll
      for (int dt = 0; dt < 4; ++dt) dst[dt * 16 + lq] = f2bf(oacc[dt][r] * inv);
    }
  }
}

// ---------------- launch ----------------
extern "C" void kernel_launch(void* const* d_in, const int* in_sizes, int n_in,
                              void* d_out, int out_size, void* d_ws, size_t ws_size,
                              hipStream_t stream) {
  const float* x     = (const float*)d_in[0];
  const float* w_in  = (const float*)d_in[1];
  const float* b_in  = (const float*)d_in[2];
  const float* w_out = (const float*)d_in[3];
  const float* b_out = (const float*)d_in[4];

  char* ws = (char*)d_ws;
  u16* xi_bf   = (u16*)(ws);
  u16* win_bf  = (u16*)(ws + 16777216);
  u16* wout_bf = (u16*)(ws + 16777216 + 6291456);
  u16* qkv     = (u16*)(ws + 16777216 + 6291456 + 2097152);
  u16* o_bf    = (u16*)(ws + 16777216 + 6291456 + 2097152 + 50331648);

  // 1. fused input conversion (x-gather + w_in + w_out)
  conv_all<<<6144, 256, 0, stream>>>(x, w_in, w_out, xi_bf, win_bf, wout_bf);
  // 2. QKV projection (128x256, BK=64, fused V transpose), 768 blocks = 3 exact rounds
  gemm_pipe<3072, 0><<<768, 512, 0, stream>>>(xi_bf, win_bf, b_in, qkv);
  // 3. attention (whole-head blocks, K/V LDS-resident)
  attn_kernel<<<256, 512, 0, stream>>>(qkv, o_bf);
  // 4. output projection + scatter + zero-fill, 256 blocks = 1 exact round
  gemm_pipe<1024, 1><<<256, 512, 0, stream>>>(o_bf, wout_bf, b_out, d_out);
}